// Round 1
// baseline (4032.760 us; speedup 1.0000x reference)
//
#include <hip/hip_runtime.h>
#include <hip/hip_bf16.h>

#define T_TOK 2048
#define HDIM  2048
#define NEXP  16
#define TOPK  4
#define IDIM  1408
#define ISDIM 5632
#define RSCALE 2.5f
#define RCAP   30.0f

typedef __attribute__((ext_vector_type(8))) short bf16x8;   // 8 bf16 (4 VGPRs) MFMA frag
typedef __attribute__((ext_vector_type(4))) float f32x4;    // MFMA accumulator

// fp32 -> bf16 round-to-nearest-even (no NaN inputs in this problem)
__device__ __forceinline__ short f2bf(float f) {
    union { float f; unsigned u; } v; v.f = f;
    unsigned r = v.u + 0x7fff + ((v.u >> 16) & 1);
    return (short)(r >> 16);
}

// ---------------------------------------------------------------------------
// Router: logits = x @ gate_w^T (fp32), tanh softcap, sigmoid scores,
// top-4 on (score + bias) with first-index tie-break, renormalized weights
// (x RSCALE folded in). Appends (token, weight) to per-expert lists.
// One wave per token; 4 tokens per block.
// ---------------------------------------------------------------------------
__global__ void router_kernel(const float* __restrict__ x,
                              const float* __restrict__ gate_w,
                              const float* __restrict__ bias,
                              int* __restrict__ cnt,
                              int* __restrict__ ltok,
                              float* __restrict__ lw)
{
    const int wave = threadIdx.x >> 6;
    const int lane = threadIdx.x & 63;
    const int t = blockIdx.x * 4 + wave;

    float acc[NEXP];
    #pragma unroll
    for (int e = 0; e < NEXP; e++) acc[e] = 0.f;

    const float* xr = x + (long)t * HDIM;
    for (int i = lane; i < HDIM; i += 64) {
        float xv = xr[i];
        #pragma unroll
        for (int e = 0; e < NEXP; e++) acc[e] += xv * gate_w[e * HDIM + i];
    }
    #pragma unroll
    for (int e = 0; e < NEXP; e++) {
        float v = acc[e];
        #pragma unroll
        for (int off = 32; off > 0; off >>= 1) v += __shfl_xor(v, off);
        acc[e] = v;
    }
    if (lane == 0) {
        float score[NEXP], sel[NEXP];
        #pragma unroll
        for (int e = 0; e < NEXP; e++) {
            float lg = tanhf(acc[e] / RCAP) * RCAP;
            float s = 1.f / (1.f + expf(-lg));
            score[e] = s;
            sel[e] = s + bias[e];
        }
        int ids[TOPK]; float w[TOPK]; float wsum = 0.f;
        #pragma unroll
        for (int k = 0; k < TOPK; k++) {
            int best = 0; float bv = sel[0];
            #pragma unroll
            for (int e = 1; e < NEXP; e++)
                if (sel[e] > bv) { bv = sel[e]; best = e; }   // strict > keeps lowest idx
            ids[k] = best; w[k] = score[best]; wsum += score[best];
            sel[best] = -1e30f;
        }
        float inv = RSCALE / wsum;
        #pragma unroll
        for (int k = 0; k < TOPK; k++) {
            int e = ids[k];
            int slot = atomicAdd(&cnt[e], 1);
            ltok[e * T_TOK + slot] = t;
            lw[e * T_TOK + slot] = w[k] * inv;
        }
    }
}

__global__ void prefix_kernel(const int* __restrict__ cnt, int* __restrict__ offs)
{
    if (threadIdx.x == 0) {
        int s = 0;
        for (int e = 0; e < NEXP; e++) { offs[e] = s; s += cnt[e]; }
    }
}

// ---------------------------------------------------------------------------
// Fused gate_up GEMM + SiLU*mul epilogue.
// Tile 128(M) x 128(N) x 64(K); 4 waves, each 64x64 (4x4 of 16x16x32 MFMA).
// A: (gathered) x rows fp32 -> bf16 in LDS, k-contiguous.
// B: weight [K][2*NH] fp32 -> TRANSPOSED bf16 [n][k] in LDS (both g and u tile).
// LDS rows of 64 bf16 = 8 chunks of 16B; chunk index XOR (row&7) kills
// bank conflicts for both staged b128 writes and frag b128 reads.
// ---------------------------------------------------------------------------
template<int ROUTED>
__global__ __launch_bounds__(256, 2)
void gate_up_kernel(const float* __restrict__ X,
                    const float* __restrict__ W,
                    const int* __restrict__ cnt,
                    const int* __restrict__ offs,
                    const int* __restrict__ ltok,
                    short* __restrict__ act,
                    int NH)
{
    const int e = ROUTED ? blockIdx.z : 0;
    const int nrows = ROUTED ? cnt[e] : T_TOK;
    const int row0 = blockIdx.y * 128;
    if (row0 >= nrows) return;
    const int n0 = blockIdx.x * 128;
    const long ldw = 2L * NH;
    const float* Wb = ROUTED ? (W + (long)e * HDIM * ldw) : W;
    const int abase = ROUTED ? offs[e] : 0;
    const int* tl = ltok + e * T_TOK;

    __shared__ short lds[3 * 128 * 64];
    short* As = lds;
    short* Bg = lds + 128 * 64;
    short* Bu = lds + 2 * 128 * 64;

    const int tid = threadIdx.x;
    const int lane = tid & 63;
    const int wave = tid >> 6;
    const int wr = (wave & 1) << 6;
    const int wc = (wave >> 1) << 6;
    const int lm = lane & 15;
    const int quad = lane >> 4;

    // A staging assignment: row = g*32 + (tid>>3), chunk kc = tid&7 (8 floats)
    const int kc = tid & 7;
    const int arow_b = tid >> 3;
    long asrc[4];
    #pragma unroll
    for (int g = 0; g < 4; g++) {
        int row = g * 32 + arow_b;
        int rr = row0 + row;
        if (ROUTED) {
            int cl = rr < nrows - 1 ? rr : nrows - 1;
            rr = tl[cl];
        }
        asrc[g] = (long)rr * HDIM + kc * 8;
    }
    // B staging assignment: n = tid&127, kb = g*2 + (tid>>7)
    const int bn = tid & 127;
    const int kb0 = tid >> 7;

    f32x4 accg[4][4], accu[4][4];
    #pragma unroll
    for (int i = 0; i < 4; i++)
        #pragma unroll
        for (int j = 0; j < 4; j++) {
            accg[i][j] = (f32x4){0.f, 0.f, 0.f, 0.f};
            accu[i][j] = (f32x4){0.f, 0.f, 0.f, 0.f};
        }

    const bf16x8* As8 = (const bf16x8*)As;
    const bf16x8* Bg8 = (const bf16x8*)Bg;
    const bf16x8* Bu8 = (const bf16x8*)Bu;

    for (int k0 = 0; k0 < HDIM; k0 += 64) {
        // ---- stage A (8 consecutive fp32 -> one b128 LDS write) ----
        #pragma unroll
        for (int g = 0; g < 4; g++) {
            int row = g * 32 + arow_b;
            const float* p = X + asrc[g] + k0;
            bf16x8 v;
            #pragma unroll
            for (int j = 0; j < 8; j++) v[j] = f2bf(p[j]);
            ((bf16x8*)As)[row * 8 + (kc ^ (row & 7))] = v;
        }
        // ---- stage Bg/Bu transposed: 8 k-rows at fixed n ----
        #pragma unroll
        for (int g = 0; g < 4; g++) {
            int kb = g * 2 + kb0;
            const float* pg = Wb + (long)(k0 + kb * 8) * ldw + n0 + bn;
            bf16x8 vg, vu;
            #pragma unroll
            for (int j = 0; j < 8; j++) {
                vg[j] = f2bf(pg[(long)j * ldw]);
                vu[j] = f2bf(pg[(long)j * ldw + NH]);
            }
            int idx = bn * 8 + (kb ^ (bn & 7));
            ((bf16x8*)Bg)[idx] = vg;
            ((bf16x8*)Bu)[idx] = vu;
        }
        __syncthreads();
        // ---- 2 K-steps of 16 MFMA each (per accumulator set) ----
        #pragma unroll
        for (int ks = 0; ks < 2; ks++) {
            bf16x8 af[4], bgf[4], buf_[4];
            int c = ks * 4 + quad;
            #pragma unroll
            for (int mi = 0; mi < 4; mi++) {
                int row = wr + mi * 16 + lm;
                af[mi] = As8[row * 8 + (c ^ (row & 7))];
            }
            #pragma unroll
            for (int ni = 0; ni < 4; ni++) {
                int row = wc + ni * 16 + lm;
                int idx = row * 8 + (c ^ (row & 7));
                bgf[ni] = Bg8[idx];
                buf_[ni] = Bu8[idx];
            }
            #pragma unroll
            for (int mi = 0; mi < 4; mi++)
                #pragma unroll
                for (int ni = 0; ni < 4; ni++) {
                    accg[mi][ni] = __builtin_amdgcn_mfma_f32_16x16x32_bf16(
                        af[mi], bgf[ni], accg[mi][ni], 0, 0, 0);
                    accu[mi][ni] = __builtin_amdgcn_mfma_f32_16x16x32_bf16(
                        af[mi], buf_[ni], accu[mi][ni], 0, 0, 0);
                }
        }
        __syncthreads();
    }
    // ---- epilogue: act = silu(g) * u, store bf16 ----
    #pragma unroll
    for (int mi = 0; mi < 4; mi++) {
        #pragma unroll
        for (int r = 0; r < 4; r++) {
            int grow = row0 + wr + mi * 16 + quad * 4 + r;
            if (grow < nrows) {
                long ro = (long)(abase + grow) * NH + n0 + wc + lm;
                #pragma unroll
                for (int ni = 0; ni < 4; ni++) {
                    float gv = accg[mi][ni][r];
                    float uv = accu[mi][ni][r];
                    float s = gv / (1.f + __expf(-gv)) * uv;
                    act[ro + ni * 16] = f2bf(s);
                }
            }
        }
    }
}

// ---------------------------------------------------------------------------
// Down GEMM: C = act(bf16) @ W(fp32 [K][H]).
// ROUTED: atomicAdd(out[tok], val * (norm_weight*SCALE)); else plain store.
// ---------------------------------------------------------------------------
template<int ROUTED>
__global__ __launch_bounds__(256, 2)
void down_kernel(const short* __restrict__ act,
                 const float* __restrict__ W,
                 const int* __restrict__ cnt,
                 const int* __restrict__ offs,
                 const int* __restrict__ ltok,
                 const float* __restrict__ lw,
                 float* __restrict__ out,
                 int Kdim)
{
    const int e = ROUTED ? blockIdx.z : 0;
    const int nrows = ROUTED ? cnt[e] : T_TOK;
    const int row0 = blockIdx.y * 128;
    if (row0 >= nrows) return;
    const int n0 = blockIdx.x * 128;
    const float* Wb = ROUTED ? (W + (long)e * Kdim * HDIM) : W;
    const int abase = ROUTED ? offs[e] : 0;

    __shared__ short lds[2 * 128 * 64];
    short* As = lds;
    short* Bs = lds + 128 * 64;

    const int tid = threadIdx.x;
    const int lane = tid & 63;
    const int wave = tid >> 6;
    const int wr = (wave & 1) << 6;
    const int wc = (wave >> 1) << 6;
    const int lm = lane & 15;
    const int quad = lane >> 4;

    const int kc = tid & 7;
    const int arow_b = tid >> 3;
    long asrc[4];
    #pragma unroll
    for (int g = 0; g < 4; g++) {
        int row = g * 32 + arow_b;
        int rr = row0 + row;
        int cl = rr < nrows - 1 ? rr : nrows - 1;
        asrc[g] = (long)(abase + cl) * Kdim + kc * 8;
    }
    const int bn = tid & 127;
    const int kb0 = tid >> 7;

    f32x4 acc[4][4];
    #pragma unroll
    for (int i = 0; i < 4; i++)
        #pragma unroll
        for (int j = 0; j < 4; j++) acc[i][j] = (f32x4){0.f, 0.f, 0.f, 0.f};

    const bf16x8* As8 = (const bf16x8*)As;
    const bf16x8* Bs8 = (const bf16x8*)Bs;

    for (int k0 = 0; k0 < Kdim; k0 += 64) {
        #pragma unroll
        for (int g = 0; g < 4; g++) {
            int row = g * 32 + arow_b;
            bf16x8 v = *(const bf16x8*)(act + asrc[g] + k0);   // already bf16
            ((bf16x8*)As)[row * 8 + (kc ^ (row & 7))] = v;
        }
        #pragma unroll
        for (int g = 0; g < 4; g++) {
            int kb = g * 2 + kb0;
            const float* p = Wb + (long)(k0 + kb * 8) * HDIM + n0 + bn;
            bf16x8 v;
            #pragma unroll
            for (int j = 0; j < 8; j++) v[j] = f2bf(p[(long)j * HDIM]);
            ((bf16x8*)Bs)[bn * 8 + (kb ^ (bn & 7))] = v;
        }
        __syncthreads();
        #pragma unroll
        for (int ks = 0; ks < 2; ks++) {
            bf16x8 af[4], bf_[4];
            int c = ks * 4 + quad;
            #pragma unroll
            for (int mi = 0; mi < 4; mi++) {
                int row = wr + mi * 16 + lm;
                af[mi] = As8[row * 8 + (c ^ (row & 7))];
            }
            #pragma unroll
            for (int ni = 0; ni < 4; ni++) {
                int row = wc + ni * 16 + lm;
                bf_[ni] = Bs8[row * 8 + (c ^ (row & 7))];
            }
            #pragma unroll
            for (int mi = 0; mi < 4; mi++)
                #pragma unroll
                for (int ni = 0; ni < 4; ni++)
                    acc[mi][ni] = __builtin_amdgcn_mfma_f32_16x16x32_bf16(
                        af[mi], bf_[ni], acc[mi][ni], 0, 0, 0);
        }
        __syncthreads();
    }
    if (ROUTED) {
        #pragma unroll
        for (int mi = 0; mi < 4; mi++)
            #pragma unroll
            for (int r = 0; r < 4; r++) {
                int grow = row0 + wr + mi * 16 + quad * 4 + r;
                if (grow < nrows) {
                    int tok = ltok[e * T_TOK + grow];
                    float wgt = lw[e * T_TOK + grow];
                    float* orow = out + (long)tok * HDIM + n0 + wc + lm;
                    #pragma unroll
                    for (int ni = 0; ni < 4; ni++)
                        atomicAdd(orow + ni * 16, acc[mi][ni][r] * wgt);
                }
            }
    } else {
        #pragma unroll
        for (int mi = 0; mi < 4; mi++)
            #pragma unroll
            for (int r = 0; r < 4; r++) {
                int grow = row0 + wr + mi * 16 + quad * 4 + r;
                float* orow = out + (long)grow * HDIM + n0 + wc + lm;
                #pragma unroll
                for (int ni = 0; ni < 4; ni++)
                    orow[ni * 16] = acc[mi][ni][r];
            }
    }
}

// ---------------------------------------------------------------------------
// Workspace layout (bytes):
//   0        cnt[16]                (zeroed each launch)
//   256      offs[16]
//   512      ltok[16][2048] int     (128 KiB)
//   131584   lw  [16][2048] float   (128 KiB)
//   262656   act_routed bf16 [8192][1408]  (23068672 B, packed by offs[e])
//   23331328 act_shared bf16 [2048][5632]  (23068672 B)
//   total 46400000 B
// ---------------------------------------------------------------------------
extern "C" void kernel_launch(void* const* d_in, const int* in_sizes, int n_in,
                              void* d_out, int out_size, void* d_ws, size_t ws_size,
                              hipStream_t stream)
{
    const float* x   = (const float*)d_in[0];
    const float* gw  = (const float*)d_in[1];
    const float* cb  = (const float*)d_in[2];
    const float* wgu = (const float*)d_in[3];
    const float* wd  = (const float*)d_in[4];
    const float* sgu = (const float*)d_in[5];
    const float* sd  = (const float*)d_in[6];
    float* out = (float*)d_out;

    char* ws = (char*)d_ws;
    int*   cnt  = (int*)(ws + 0);
    int*   offs = (int*)(ws + 256);
    int*   ltok = (int*)(ws + 512);
    float* lw   = (float*)(ws + 131584);
    short* actR = (short*)(ws + 262656);
    short* actS = (short*)(ws + 23331328);

    hipMemsetAsync(cnt, 0, 64, stream);
    router_kernel<<<T_TOK / 4, 256, 0, stream>>>(x, gw, cb, cnt, ltok, lw);
    prefix_kernel<<<1, 64, 0, stream>>>(cnt, offs);

    // shared expert: gate_up+silu -> actS ; down -> out (plain store)
    gate_up_kernel<0><<<dim3(ISDIM / 128, T_TOK / 128, 1), 256, 0, stream>>>(
        x, sgu, cnt, offs, ltok, actS, ISDIM);
    down_kernel<0><<<dim3(HDIM / 128, T_TOK / 128, 1), 256, 0, stream>>>(
        actS, sd, cnt, offs, ltok, lw, out, ISDIM);

    // routed experts: grouped gate_up+silu -> actR ; down -> atomicAdd into out
    gate_up_kernel<1><<<dim3(IDIM / 128, T_TOK / 128, NEXP), 256, 0, stream>>>(
        x, wgu, cnt, offs, ltok, actR, IDIM);
    down_kernel<1><<<dim3(HDIM / 128, T_TOK / 128, NEXP), 256, 0, stream>>>(
        actR, wd, cnt, offs, ltok, lw, out, IDIM);
}

// Round 2
// 1341.970 us; speedup vs baseline: 3.0051x; 3.0051x over previous
//
#include <hip/hip_runtime.h>
#include <hip/hip_bf16.h>

#define T_TOK 2048
#define HDIM  2048
#define NEXP  16
#define TOPK  4
#define IDIM  1408
#define ISDIM 5632
#define RSCALE 2.5f
#define RCAP   30.0f

typedef __attribute__((ext_vector_type(8))) short bf16x8;   // 8 bf16 (4 VGPRs) MFMA frag
typedef __attribute__((ext_vector_type(4))) float f32x4;    // MFMA accumulator

// fp32 -> bf16 round-to-nearest-even (no NaN inputs in this problem)
__device__ __forceinline__ short f2bf(float f) {
    union { float f; unsigned u; } v; v.f = f;
    unsigned r = v.u + 0x7fff + ((v.u >> 16) & 1);
    return (short)(r >> 16);
}

// async 16B global -> LDS (DMA; LDS dest = wave-uniform base + lane*16)
__device__ __forceinline__ void async16(const void* g, void* l) {
    __builtin_amdgcn_global_load_lds(
        (const __attribute__((address_space(1))) void*)g,
        (__attribute__((address_space(3))) void*)l, 16, 0, 0);
}

// ---------------------------------------------------------------------------
// Router (unchanged from round 1): fp32 logits, tanh softcap, sigmoid scores,
// top-4 on (score+bias) with first-index tie-break, renormalized * RSCALE.
// ---------------------------------------------------------------------------
__global__ void router_kernel(const float* __restrict__ x,
                              const float* __restrict__ gate_w,
                              const float* __restrict__ bias,
                              int* __restrict__ cnt,
                              int* __restrict__ ltok,
                              float* __restrict__ lw)
{
    const int wave = threadIdx.x >> 6;
    const int lane = threadIdx.x & 63;
    const int t = blockIdx.x * 4 + wave;

    float acc[NEXP];
    #pragma unroll
    for (int e = 0; e < NEXP; e++) acc[e] = 0.f;

    const float* xr = x + (long)t * HDIM;
    for (int i = lane; i < HDIM; i += 64) {
        float xv = xr[i];
        #pragma unroll
        for (int e = 0; e < NEXP; e++) acc[e] += xv * gate_w[e * HDIM + i];
    }
    #pragma unroll
    for (int e = 0; e < NEXP; e++) {
        float v = acc[e];
        #pragma unroll
        for (int off = 32; off > 0; off >>= 1) v += __shfl_xor(v, off);
        acc[e] = v;
    }
    if (lane == 0) {
        float score[NEXP], sel[NEXP];
        #pragma unroll
        for (int e = 0; e < NEXP; e++) {
            float lg = tanhf(acc[e] / RCAP) * RCAP;
            float s = 1.f / (1.f + expf(-lg));
            score[e] = s;
            sel[e] = s + bias[e];
        }
        int ids[TOPK]; float w[TOPK]; float wsum = 0.f;
        #pragma unroll
        for (int k = 0; k < TOPK; k++) {
            int best = 0; float bv = sel[0];
            #pragma unroll
            for (int e = 1; e < NEXP; e++)
                if (sel[e] > bv) { bv = sel[e]; best = e; }
            ids[k] = best; w[k] = score[best]; wsum += score[best];
            sel[best] = -1e30f;
        }
        float inv = RSCALE / wsum;
        #pragma unroll
        for (int k = 0; k < TOPK; k++) {
            int e = ids[k];
            int slot = atomicAdd(&cnt[e], 1);
            ltok[e * T_TOK + slot] = t;
            lw[e * T_TOK + slot] = w[k] * inv;
        }
    }
}

__global__ void prefix_kernel(const int* __restrict__ cnt, int* __restrict__ offs)
{
    if (threadIdx.x == 0) {
        int s = 0;
        for (int e = 0; e < NEXP; e++) { offs[e] = s; s += cnt[e]; }
    }
}

// ---------------------------------------------------------------------------
// Transpose + convert: src fp32 [K][N] (z matrices) -> dst bf16 [N][K].
// 64x64 tiles via LDS (pad 68 shorts/row -> 8B-aligned, ~4-way conflicts ok;
// kernel is HBM-bound). grid = (N/64, K/64, Z).
// ---------------------------------------------------------------------------
__global__ __launch_bounds__(256)
void transpose_cvt(const float* __restrict__ src, short* __restrict__ dst,
                   int K, int N)
{
    const long zoff = (long)blockIdx.z * K * N;
    src += zoff; dst += zoff;
    const int k0 = blockIdx.y * 64;
    const int n0 = blockIdx.x * 64;
    __shared__ short t[64 * 68];
    const int tid = threadIdx.x;
    const int rk = tid >> 4;          // 0..15
    const int rn = (tid & 15) * 4;
    #pragma unroll
    for (int g = 0; g < 4; g++) {
        int kk = g * 16 + rk;
        const float* p = src + (long)(k0 + kk) * N + n0 + rn;
        float4 v = *(const float4*)p;
        short* d = &t[kk * 68 + rn];
        d[0] = f2bf(v.x); d[1] = f2bf(v.y); d[2] = f2bf(v.z); d[3] = f2bf(v.w);
    }
    __syncthreads();
    #pragma unroll
    for (int h = 0; h < 2; h++) {
        int chunk = h * 256 + tid;
        int n = chunk >> 3, kc = chunk & 7;
        bf16x8 v;
        #pragma unroll
        for (int j = 0; j < 8; j++) v[j] = t[(kc * 8 + j) * 68 + n];
        *(bf16x8*)(dst + (long)(n0 + n) * K + k0 + kc * 8) = v;
    }
}

// flat fp32 -> bf16 (for x)
__global__ void cvt_bf16(const float* __restrict__ src, short* __restrict__ dst, int n)
{
    int i = (blockIdx.x * 256 + threadIdx.x) * 8;
    if (i < n) {
        float4 a = *(const float4*)(src + i);
        float4 b = *(const float4*)(src + i + 4);
        bf16x8 v;
        v[0] = f2bf(a.x); v[1] = f2bf(a.y); v[2] = f2bf(a.z); v[3] = f2bf(a.w);
        v[4] = f2bf(b.x); v[5] = f2bf(b.y); v[6] = f2bf(b.z); v[7] = f2bf(b.w);
        *(bf16x8*)(dst + i) = v;
    }
}

// ---------------------------------------------------------------------------
// FAST gate_up GEMM + SiLU*mul. A = xb (bf16, gathered rows), B = Wt bf16
// [n][k] k-contiguous. Both staged via async global_load_lds width 16.
// XOR swizzle applied at the global SOURCE chunk so that LDS lands swizzled:
//   LDS[row][c] = data[row][c ^ (row&7)]  -> ds_read_b128 conflict-free.
// Tile 128x128x64, 4 waves of 64x64 (4x4 of 16x16x32 MFMA), g+u fused.
// ---------------------------------------------------------------------------
template<int ROUTED>
__global__ __launch_bounds__(256, 2)
void gate_up_fast(const short* __restrict__ Xb,
                  const short* __restrict__ Wt,
                  const int* __restrict__ cnt,
                  const int* __restrict__ offs,
                  const int* __restrict__ ltok,
                  short* __restrict__ act,
                  int NH)
{
    const int e = ROUTED ? blockIdx.z : 0;
    const int nrows = ROUTED ? cnt[e] : T_TOK;
    const int row0 = blockIdx.y * 128;
    if (row0 >= nrows) return;
    const int n0 = blockIdx.x * 128;
    const int abase = ROUTED ? offs[e] : 0;

    __shared__ short lds[3 * 128 * 64];
    short* As = lds;
    short* Bg = lds + 128 * 64;
    short* Bu = lds + 2 * 128 * 64;

    const int tid = threadIdx.x;
    const int lane = tid & 63;
    const int wave = tid >> 6;
    const int wr = (wave & 1) << 6;
    const int wc = (wave >> 1) << 6;
    const int lm = lane & 15;
    const int quad = lane >> 4;

    const int rsel = lane >> 3;                 // 0..7 : row within 8-row group
    const int csel = lane & 7;                  // LDS chunk slot
    const int koff = ((csel ^ rsel) * 8);       // swizzled source chunk (elements)

    // per-lane source row pointers (4 issues x 8 rows per wave = 32 rows/wave)
    const short* aptr[4];
    const short* bgptr[4];
    #pragma unroll
    for (int q = 0; q < 4; q++) {
        int row = wave * 32 + q * 8 + rsel;
        int rr = row0 + row;
        if (ROUTED) {
            int cl = rr < nrows - 1 ? rr : nrows - 1;
            rr = ltok[e * T_TOK + cl];
        }
        aptr[q] = Xb + (long)rr * HDIM + koff;
        long gr = ROUTED ? ((long)e * 2 * NH + n0 + row) : (long)(n0 + row);
        bgptr[q] = Wt + gr * HDIM + koff;
    }
    const long upoff = (long)NH * HDIM;

    f32x4 accg[4][4], accu[4][4];
    #pragma unroll
    for (int i = 0; i < 4; i++)
        #pragma unroll
        for (int j = 0; j < 4; j++) {
            accg[i][j] = (f32x4){0.f, 0.f, 0.f, 0.f};
            accu[i][j] = (f32x4){0.f, 0.f, 0.f, 0.f};
        }

    const bf16x8* As8 = (const bf16x8*)As;
    const bf16x8* Bg8 = (const bf16x8*)Bg;
    const bf16x8* Bu8 = (const bf16x8*)Bu;

    for (int k0 = 0; k0 < HDIM; k0 += 64) {
        #pragma unroll
        for (int q = 0; q < 4; q++) {
            int lb = (wave * 32 + q * 8) * 64;      // LDS short index of 8-row group
            async16(aptr[q] + k0, As + lb);
            async16(bgptr[q] + k0, Bg + lb);
            async16(bgptr[q] + upoff + k0, Bu + lb);
        }
        __syncthreads();   // drains vmcnt -> LDS tiles complete
        #pragma unroll
        for (int ks = 0; ks < 2; ks++) {
            bf16x8 af[4], bgf[4], buf_[4];
            int c = ks * 4 + quad;
            #pragma unroll
            for (int mi = 0; mi < 4; mi++) {
                int row = wr + mi * 16 + lm;
                af[mi] = As8[row * 8 + (c ^ (row & 7))];
            }
            #pragma unroll
            for (int ni = 0; ni < 4; ni++) {
                int row = wc + ni * 16 + lm;
                int idx = row * 8 + (c ^ (row & 7));
                bgf[ni] = Bg8[idx];
                buf_[ni] = Bu8[idx];
            }
            #pragma unroll
            for (int mi = 0; mi < 4; mi++)
                #pragma unroll
                for (int ni = 0; ni < 4; ni++) {
                    accg[mi][ni] = __builtin_amdgcn_mfma_f32_16x16x32_bf16(
                        af[mi], bgf[ni], accg[mi][ni], 0, 0, 0);
                    accu[mi][ni] = __builtin_amdgcn_mfma_f32_16x16x32_bf16(
                        af[mi], buf_[ni], accu[mi][ni], 0, 0, 0);
                }
        }
        __syncthreads();
    }
    #pragma unroll
    for (int mi = 0; mi < 4; mi++) {
        #pragma unroll
        for (int r = 0; r < 4; r++) {
            int grow = row0 + wr + mi * 16 + quad * 4 + r;
            if (grow < nrows) {
                long ro = (long)(abase + grow) * NH + n0 + wc + lm;
                #pragma unroll
                for (int ni = 0; ni < 4; ni++) {
                    float gv = accg[mi][ni][r];
                    float uv = accu[mi][ni][r];
                    float s = gv / (1.f + __expf(-gv)) * uv;
                    act[ro + ni * 16] = f2bf(s);
                }
            }
        }
    }
}

// ---------------------------------------------------------------------------
// FAST down GEMM: C = act(bf16 packed rows) @ Wt(bf16 [n][k]).
// ROUTED: atomicAdd(out[tok], val * weight); else plain store.
// ---------------------------------------------------------------------------
template<int ROUTED>
__global__ __launch_bounds__(256, 2)
void down_fast(const short* __restrict__ act,
               const short* __restrict__ Wt,
               const int* __restrict__ cnt,
               const int* __restrict__ offs,
               const int* __restrict__ ltok,
               const float* __restrict__ lw,
               float* __restrict__ out,
               int Kdim)
{
    const int e = ROUTED ? blockIdx.z : 0;
    const int nrows = ROUTED ? cnt[e] : T_TOK;
    const int row0 = blockIdx.y * 128;
    if (row0 >= nrows) return;
    const int n0 = blockIdx.x * 128;
    const int abase = ROUTED ? offs[e] : 0;

    __shared__ short lds[2 * 128 * 64];
    short* As = lds;
    short* Bs = lds + 128 * 64;

    const int tid = threadIdx.x;
    const int lane = tid & 63;
    const int wave = tid >> 6;
    const int wr = (wave & 1) << 6;
    const int wc = (wave >> 1) << 6;
    const int lm = lane & 15;
    const int quad = lane >> 4;

    const int rsel = lane >> 3;
    const int csel = lane & 7;
    const int koff = ((csel ^ rsel) * 8);

    const short* aptr[4];
    const short* bptr[4];
    #pragma unroll
    for (int q = 0; q < 4; q++) {
        int row = wave * 32 + q * 8 + rsel;
        int rr = row0 + row;
        int cl = rr < nrows - 1 ? rr : nrows - 1;
        aptr[q] = act + (long)(abase + cl) * Kdim + koff;
        long gr = (ROUTED ? (long)e * HDIM : 0L) + n0 + row;
        bptr[q] = Wt + gr * Kdim + koff;
    }

    f32x4 acc[4][4];
    #pragma unroll
    for (int i = 0; i < 4; i++)
        #pragma unroll
        for (int j = 0; j < 4; j++) acc[i][j] = (f32x4){0.f, 0.f, 0.f, 0.f};

    const bf16x8* As8 = (const bf16x8*)As;
    const bf16x8* Bs8 = (const bf16x8*)Bs;

    for (int k0 = 0; k0 < Kdim; k0 += 64) {
        #pragma unroll
        for (int q = 0; q < 4; q++) {
            int lb = (wave * 32 + q * 8) * 64;
            async16(aptr[q] + k0, As + lb);
            async16(bptr[q] + k0, Bs + lb);
        }
        __syncthreads();
        #pragma unroll
        for (int ks = 0; ks < 2; ks++) {
            bf16x8 af[4], bf_[4];
            int c = ks * 4 + quad;
            #pragma unroll
            for (int mi = 0; mi < 4; mi++) {
                int row = wr + mi * 16 + lm;
                af[mi] = As8[row * 8 + (c ^ (row & 7))];
            }
            #pragma unroll
            for (int ni = 0; ni < 4; ni++) {
                int row = wc + ni * 16 + lm;
                bf_[ni] = Bs8[row * 8 + (c ^ (row & 7))];
            }
            #pragma unroll
            for (int mi = 0; mi < 4; mi++)
                #pragma unroll
                for (int ni = 0; ni < 4; ni++)
                    acc[mi][ni] = __builtin_amdgcn_mfma_f32_16x16x32_bf16(
                        af[mi], bf_[ni], acc[mi][ni], 0, 0, 0);
        }
        __syncthreads();
    }
    if (ROUTED) {
        #pragma unroll
        for (int mi = 0; mi < 4; mi++)
            #pragma unroll
            for (int r = 0; r < 4; r++) {
                int grow = row0 + wr + mi * 16 + quad * 4 + r;
                if (grow < nrows) {
                    int tok = ltok[e * T_TOK + grow];
                    float wgt = lw[e * T_TOK + grow];
                    float* orow = out + (long)tok * HDIM + n0 + wc + lm;
                    #pragma unroll
                    for (int ni = 0; ni < 4; ni++)
                        atomicAdd(orow + ni * 16, acc[mi][ni][r] * wgt);
                }
            }
    } else {
        #pragma unroll
        for (int mi = 0; mi < 4; mi++)
            #pragma unroll
            for (int r = 0; r < 4; r++) {
                int grow = row0 + wr + mi * 16 + quad * 4 + r;
                float* orow = out + (long)grow * HDIM + n0 + wc + lm;
                #pragma unroll
                for (int ni = 0; ni < 4; ni++)
                    orow[ni * 16] = acc[mi][ni][r];
            }
    }
}

// ===========================================================================
// SLOW fallback (round-1 verified kernels) — used only if ws_size is too
// small for the transposed-bf16 weight cache.
// ===========================================================================
template<int ROUTED>
__global__ __launch_bounds__(256, 2)
void gate_up_slow(const float* __restrict__ X, const float* __restrict__ W,
                  const int* __restrict__ cnt, const int* __restrict__ offs,
                  const int* __restrict__ ltok, short* __restrict__ act, int NH)
{
    const int e = ROUTED ? blockIdx.z : 0;
    const int nrows = ROUTED ? cnt[e] : T_TOK;
    const int row0 = blockIdx.y * 128;
    if (row0 >= nrows) return;
    const int n0 = blockIdx.x * 128;
    const long ldw = 2L * NH;
    const float* Wb = ROUTED ? (W + (long)e * HDIM * ldw) : W;
    const int abase = ROUTED ? offs[e] : 0;
    const int* tl = ltok + e * T_TOK;

    __shared__ short lds[3 * 128 * 64];
    short* As = lds; short* Bg = lds + 128 * 64; short* Bu = lds + 2 * 128 * 64;
    const int tid = threadIdx.x, lane = tid & 63, wave = tid >> 6;
    const int wr = (wave & 1) << 6, wc = (wave >> 1) << 6;
    const int lm = lane & 15, quad = lane >> 4;
    const int kc = tid & 7, arow_b = tid >> 3;
    long asrc[4];
    #pragma unroll
    for (int g = 0; g < 4; g++) {
        int row = g * 32 + arow_b, rr = row0 + row;
        if (ROUTED) { int cl = rr < nrows - 1 ? rr : nrows - 1; rr = tl[cl]; }
        asrc[g] = (long)rr * HDIM + kc * 8;
    }
    const int bn = tid & 127, kb0 = tid >> 7;
    f32x4 accg[4][4], accu[4][4];
    #pragma unroll
    for (int i = 0; i < 4; i++)
        #pragma unroll
        for (int j = 0; j < 4; j++) {
            accg[i][j] = (f32x4){0.f,0.f,0.f,0.f}; accu[i][j] = (f32x4){0.f,0.f,0.f,0.f};
        }
    const bf16x8* As8 = (const bf16x8*)As;
    const bf16x8* Bg8 = (const bf16x8*)Bg;
    const bf16x8* Bu8 = (const bf16x8*)Bu;
    for (int k0 = 0; k0 < HDIM; k0 += 64) {
        #pragma unroll
        for (int g = 0; g < 4; g++) {
            int row = g * 32 + arow_b;
            const float* p = X + asrc[g] + k0;
            bf16x8 v;
            #pragma unroll
            for (int j = 0; j < 8; j++) v[j] = f2bf(p[j]);
            ((bf16x8*)As)[row * 8 + (kc ^ (row & 7))] = v;
        }
        #pragma unroll
        for (int g = 0; g < 4; g++) {
            int kb = g * 2 + kb0;
            const float* pg = Wb + (long)(k0 + kb * 8) * ldw + n0 + bn;
            bf16x8 vg, vu;
            #pragma unroll
            for (int j = 0; j < 8; j++) {
                vg[j] = f2bf(pg[(long)j * ldw]); vu[j] = f2bf(pg[(long)j * ldw + NH]);
            }
            int idx = bn * 8 + (kb ^ (bn & 7));
            ((bf16x8*)Bg)[idx] = vg; ((bf16x8*)Bu)[idx] = vu;
        }
        __syncthreads();
        #pragma unroll
        for (int ks = 0; ks < 2; ks++) {
            bf16x8 af[4], bgf[4], buf_[4];
            int c = ks * 4 + quad;
            #pragma unroll
            for (int mi = 0; mi < 4; mi++) {
                int row = wr + mi * 16 + lm;
                af[mi] = As8[row * 8 + (c ^ (row & 7))];
            }
            #pragma unroll
            for (int ni = 0; ni < 4; ni++) {
                int row = wc + ni * 16 + lm;
                int idx = row * 8 + (c ^ (row & 7));
                bgf[ni] = Bg8[idx]; buf_[ni] = Bu8[idx];
            }
            #pragma unroll
            for (int mi = 0; mi < 4; mi++)
                #pragma unroll
                for (int ni = 0; ni < 4; ni++) {
                    accg[mi][ni] = __builtin_amdgcn_mfma_f32_16x16x32_bf16(af[mi], bgf[ni], accg[mi][ni], 0,0,0);
                    accu[mi][ni] = __builtin_amdgcn_mfma_f32_16x16x32_bf16(af[mi], buf_[ni], accu[mi][ni], 0,0,0);
                }
        }
        __syncthreads();
    }
    #pragma unroll
    for (int mi = 0; mi < 4; mi++)
        #pragma unroll
        for (int r = 0; r < 4; r++) {
            int grow = row0 + wr + mi * 16 + quad * 4 + r;
            if (grow < nrows) {
                long ro = (long)(abase + grow) * NH + n0 + wc + lm;
                #pragma unroll
                for (int ni = 0; ni < 4; ni++) {
                    float gv = accg[mi][ni][r], uv = accu[mi][ni][r];
                    act[ro + ni * 16] = f2bf(gv / (1.f + __expf(-gv)) * uv);
                }
            }
        }
}

template<int ROUTED>
__global__ __launch_bounds__(256, 2)
void down_slow(const short* __restrict__ act, const float* __restrict__ W,
               const int* __restrict__ cnt, const int* __restrict__ offs,
               const int* __restrict__ ltok, const float* __restrict__ lw,
               float* __restrict__ out, int Kdim)
{
    const int e = ROUTED ? blockIdx.z : 0;
    const int nrows = ROUTED ? cnt[e] : T_TOK;
    const int row0 = blockIdx.y * 128;
    if (row0 >= nrows) return;
    const int n0 = blockIdx.x * 128;
    const float* Wb = ROUTED ? (W + (long)e * Kdim * HDIM) : W;
    const int abase = ROUTED ? offs[e] : 0;
    __shared__ short lds[2 * 128 * 64];
    short* As = lds; short* Bs = lds + 128 * 64;
    const int tid = threadIdx.x, lane = tid & 63, wave = tid >> 6;
    const int wr = (wave & 1) << 6, wc = (wave >> 1) << 6;
    const int lm = lane & 15, quad = lane >> 4;
    const int kc = tid & 7, arow_b = tid >> 3;
    long asrc[4];
    #pragma unroll
    for (int g = 0; g < 4; g++) {
        int row = g * 32 + arow_b, rr = row0 + row;
        int cl = rr < nrows - 1 ? rr : nrows - 1;
        asrc[g] = (long)(abase + cl) * Kdim + kc * 8;
    }
    const int bn = tid & 127, kb0 = tid >> 7;
    f32x4 acc[4][4];
    #pragma unroll
    for (int i = 0; i < 4; i++)
        #pragma unroll
        for (int j = 0; j < 4; j++) acc[i][j] = (f32x4){0.f,0.f,0.f,0.f};
    const bf16x8* As8 = (const bf16x8*)As;
    const bf16x8* Bs8 = (const bf16x8*)Bs;
    for (int k0 = 0; k0 < Kdim; k0 += 64) {
        #pragma unroll
        for (int g = 0; g < 4; g++) {
            int row = g * 32 + arow_b;
            bf16x8 v = *(const bf16x8*)(act + asrc[g] + k0);
            ((bf16x8*)As)[row * 8 + (kc ^ (row & 7))] = v;
        }
        #pragma unroll
        for (int g = 0; g < 4; g++) {
            int kb = g * 2 + kb0;
            const float* p = Wb + (long)(k0 + kb * 8) * HDIM + n0 + bn;
            bf16x8 v;
            #pragma unroll
            for (int j = 0; j < 8; j++) v[j] = f2bf(p[(long)j * HDIM]);
            ((bf16x8*)Bs)[bn * 8 + (kb ^ (bn & 7))] = v;
        }
        __syncthreads();
        #pragma unroll
        for (int ks = 0; ks < 2; ks++) {
            bf16x8 af[4], bf_[4];
            int c = ks * 4 + quad;
            #pragma unroll
            for (int mi = 0; mi < 4; mi++) {
                int row = wr + mi * 16 + lm;
                af[mi] = As8[row * 8 + (c ^ (row & 7))];
            }
            #pragma unroll
            for (int ni = 0; ni < 4; ni++) {
                int row = wc + ni * 16 + lm;
                bf_[ni] = Bs8[row * 8 + (c ^ (row & 7))];
            }
            #pragma unroll
            for (int mi = 0; mi < 4; mi++)
                #pragma unroll
                for (int ni = 0; ni < 4; ni++)
                    acc[mi][ni] = __builtin_amdgcn_mfma_f32_16x16x32_bf16(af[mi], bf_[ni], acc[mi][ni], 0,0,0);
        }
        __syncthreads();
    }
    if (ROUTED) {
        #pragma unroll
        for (int mi = 0; mi < 4; mi++)
            #pragma unroll
            for (int r = 0; r < 4; r++) {
                int grow = row0 + wr + mi * 16 + quad * 4 + r;
                if (grow < nrows) {
                    int tok = ltok[e * T_TOK + grow];
                    float wgt = lw[e * T_TOK + grow];
                    float* orow = out + (long)tok * HDIM + n0 + wc + lm;
                    #pragma unroll
                    for (int ni = 0; ni < 4; ni++)
                        atomicAdd(orow + ni * 16, acc[mi][ni][r] * wgt);
                }
            }
    } else {
        #pragma unroll
        for (int mi = 0; mi < 4; mi++)
            #pragma unroll
            for (int r = 0; r < 4; r++) {
                int grow = row0 + wr + mi * 16 + quad * 4 + r;
                float* orow = out + (long)grow * HDIM + n0 + wc + lm;
                #pragma unroll
                for (int ni = 0; ni < 4; ni++) orow[ni * 16] = acc[mi][ni][r];
            }
    }
}

// ---------------------------------------------------------------------------
// Fast-path workspace layout (bytes):
//   0          cnt[16]
//   256        offs[16]
//   512        ltok[16][2048] int       131072
//   131584     lw  [16][2048] float     131072
//   262656     xb   bf16 [2048][2048]     8388608
//   8651264    actR bf16 [8192][1408]    23068672
//   31719936   actS bf16 [2048][5632]    23068672
//   54788608   wguT bf16 [16][2816][2048] 184549376
//   239337984  wdT  bf16 [16][2048][1408]  92274688
//   331612672  sguT bf16 [11264][2048]     46137344
//   377750016  sdT  bf16 [2048][5632]      23068672
//   total NEED = 400818688
// ---------------------------------------------------------------------------
extern "C" void kernel_launch(void* const* d_in, const int* in_sizes, int n_in,
                              void* d_out, int out_size, void* d_ws, size_t ws_size,
                              hipStream_t stream)
{
    const float* x   = (const float*)d_in[0];
    const float* gw  = (const float*)d_in[1];
    const float* cb  = (const float*)d_in[2];
    const float* wgu = (const float*)d_in[3];
    const float* wd  = (const float*)d_in[4];
    const float* sgu = (const float*)d_in[5];
    const float* sd  = (const float*)d_in[6];
    float* out = (float*)d_out;

    char* ws = (char*)d_ws;
    const size_t NEED = 400818688ULL;

    if (ws_size >= NEED) {
        int*   cnt  = (int*)(ws + 0);
        int*   offs = (int*)(ws + 256);
        int*   ltok = (int*)(ws + 512);
        float* lw   = (float*)(ws + 131584);
        short* xb   = (short*)(ws + 262656);
        short* actR = (short*)(ws + 8651264);
        short* actS = (short*)(ws + 31719936);
        short* wguT = (short*)(ws + 54788608);
        short* wdT  = (short*)(ws + 239337984);
        short* sguT = (short*)(ws + 331612672);
        short* sdT  = (short*)(ws + 377750016);

        hipMemsetAsync(cnt, 0, 64, stream);
        router_kernel<<<T_TOK / 4, 256, 0, stream>>>(x, gw, cb, cnt, ltok, lw);
        prefix_kernel<<<1, 64, 0, stream>>>(cnt, offs);

        // weight transpose+convert passes (fp32 [K][N] -> bf16 [N][K])
        cvt_bf16<<<(T_TOK * HDIM) / (256 * 8), 256, 0, stream>>>(x, xb, T_TOK * HDIM);
        transpose_cvt<<<dim3((2 * IDIM) / 64, HDIM / 64, NEXP), 256, 0, stream>>>(
            wgu, wguT, HDIM, 2 * IDIM);
        transpose_cvt<<<dim3(HDIM / 64, IDIM / 64, NEXP), 256, 0, stream>>>(
            wd, wdT, IDIM, HDIM);
        transpose_cvt<<<dim3((2 * ISDIM) / 64, HDIM / 64, 1), 256, 0, stream>>>(
            sgu, sguT, HDIM, 2 * ISDIM);
        transpose_cvt<<<dim3(HDIM / 64, ISDIM / 64, 1), 256, 0, stream>>>(
            sd, sdT, ISDIM, HDIM);

        // shared expert
        gate_up_fast<0><<<dim3(ISDIM / 128, T_TOK / 128, 1), 256, 0, stream>>>(
            xb, sguT, cnt, offs, ltok, actS, ISDIM);
        down_fast<0><<<dim3(HDIM / 128, T_TOK / 128, 1), 256, 0, stream>>>(
            actS, sdT, cnt, offs, ltok, lw, out, ISDIM);

        // routed experts
        gate_up_fast<1><<<dim3(IDIM / 128, T_TOK / 128, NEXP), 256, 0, stream>>>(
            xb, wguT, cnt, offs, ltok, actR, IDIM);
        down_fast<1><<<dim3(HDIM / 128, T_TOK / 128, NEXP), 256, 0, stream>>>(
            actR, wdT, cnt, offs, ltok, lw, out, IDIM);
    } else {
        // fallback: round-1 layout (46.4 MB)
        int*   cnt  = (int*)(ws + 0);
        int*   offs = (int*)(ws + 256);
        int*   ltok = (int*)(ws + 512);
        float* lw   = (float*)(ws + 131584);
        short* actR = (short*)(ws + 262656);
        short* actS = (short*)(ws + 23331328);

        hipMemsetAsync(cnt, 0, 64, stream);
        router_kernel<<<T_TOK / 4, 256, 0, stream>>>(x, gw, cb, cnt, ltok, lw);
        prefix_kernel<<<1, 64, 0, stream>>>(cnt, offs);

        gate_up_slow<0><<<dim3(ISDIM / 128, T_TOK / 128, 1), 256, 0, stream>>>(
            x, sgu, cnt, offs, ltok, actS, ISDIM);
        down_slow<0><<<dim3(HDIM / 128, T_TOK / 128, 1), 256, 0, stream>>>(
            actS, sd, cnt, offs, ltok, lw, out, ISDIM);
        gate_up_slow<1><<<dim3(IDIM / 128, T_TOK / 128, NEXP), 256, 0, stream>>>(
            x, wgu, cnt, offs, ltok, actR, IDIM);
        down_slow<1><<<dim3(HDIM / 128, T_TOK / 128, NEXP), 256, 0, stream>>>(
            actR, wd, cnt, offs, ltok, lw, out, IDIM);
    }
}